// Round 6
// baseline (1442.551 us; speedup 1.0000x reference)
//
#include <hip/hip_runtime.h>
#include <hip/hip_bf16.h>
#include <stdint.h>

#define Bn 256
#define Tn 512
#define Hn 128
#define G4 512   // 4*H
#define Mn (Bn*Tn)

typedef __attribute__((ext_vector_type(8))) short s16x8;
typedef __attribute__((ext_vector_type(4))) float f32x4;

__device__ __forceinline__ float b2f(unsigned short u) {
    union { unsigned int i; float f; } v; v.i = ((unsigned int)u) << 16; return v.f;
}
__device__ __forceinline__ unsigned short f2b(float f) {
    union { float f; unsigned int i; } v; v.f = f;
    unsigned int x = v.i;
    unsigned int r = (x + 0x7FFFu + ((x >> 16) & 1u)) >> 16;
    return (unsigned short)r;
}
__device__ __forceinline__ unsigned int pk2(float a, float b) {
    __hip_bfloat162 t = __float22bfloat162_rn(make_float2(a, b));
    union { __hip_bfloat162 v; unsigned int u; } c; c.v = t; return c.u;
}
__device__ __forceinline__ s16x8 cvt8v(const float* p) {
    f32x4 a = *(const f32x4*)p;
    f32x4 b = *(const f32x4*)(p + 4);
    s16x8 r;
    r[0] = (short)f2b(a[0]); r[1] = (short)f2b(a[1]);
    r[2] = (short)f2b(a[2]); r[3] = (short)f2b(a[3]);
    r[4] = (short)f2b(b[0]); r[5] = (short)f2b(b[1]);
    r[6] = (short)f2b(b[2]); r[7] = (short)f2b(b[3]);
    return r;
}
__device__ __forceinline__ float sigm(float x) {
    return __builtin_amdgcn_rcpf(1.f + __expf(-x));
}
__device__ __forceinline__ float tanh_f(float x) {
    return 1.f - 2.f * __builtin_amdgcn_rcpf(1.f + __expf(2.f * x));
}
__device__ __forceinline__ void gload16(const void* gsrc, void* lds) {
    __builtin_amdgcn_global_load_lds(
        (const __attribute__((address_space(1))) unsigned int*)gsrc,
        (__attribute__((address_space(3))) unsigned int*)lds, 16, 0, 0);
}
// LDS-only barrier: waits DS ops but NOT outstanding global loads/stores.
__device__ __forceinline__ void ldsbar() {
    asm volatile("s_waitcnt lgkmcnt(0)\n\ts_barrier" ::: "memory");
}

// ---------------------------------------------------------------------------
// prep (unchanged, passing)
// ---------------------------------------------------------------------------
__global__ __launch_bounds__(256)
void prep(const float* __restrict__ x,
          const float* __restrict__ w0f, const float* __restrict__ w0b,
          const float* __restrict__ w1f, const float* __restrict__ w1b,
          unsigned short* __restrict__ xb,
          unsigned short* __restrict__ w0bf,
          unsigned short* __restrict__ w1bf)
{
    int tid = blockIdx.x * 256 + threadIdx.x;
    int nthr = gridDim.x * 256;
    for (int idx = tid; idx < Mn * 32; idx += nthr) {
        int row = idx >> 5, col = idx & 31;
        xb[idx] = f2b(col < 24 ? x[row * 24 + col] : 0.f);
    }
    for (int idx = tid; idx < 2 * 512 * 32; idx += nthr) {
        int d = idx >> 14, rem = idx & 16383;
        int n = rem >> 5, col = rem & 31;
        const float* w = d ? w0b : w0f;
        w0bf[idx] = f2b(col < 24 ? w[n * 24 + col] : 0.f);
    }
    for (int idx = tid; idx < 2 * 512 * 256; idx += nthr) {
        int d = idx >> 17, rem = idx & 131071;
        const float* w = d ? w1b : w1f;
        w1bf[idx] = f2b(w[rem]);
    }
}

// ---------------------------------------------------------------------------
// Tiled GEMM (unchanged, passing)
// ---------------------------------------------------------------------------
template<int BK, int KOUT>
__global__ __launch_bounds__(256, 2)
void gemm_tile(const unsigned short* __restrict__ A, int lda,
               const unsigned short* __restrict__ W,
               unsigned short* __restrict__ gx)
{
    constexpr int GR = BK / 8;
    constexpr int SWM = (GR >= 8) ? 7 : (GR - 1);
    constexpr int ASZ = 128 * BK * 2;
    constexpr int GOFF = (BK == 128) ? 0 : 2 * ASZ;
    constexpr int SMEM = 2 * ASZ + ((BK == 128) ? 0 : 4 * 16 * 68 * 4);
    __shared__ char smem[SMEM];
    unsigned short* Atile = (unsigned short*)smem;
    unsigned short* Btile = (unsigned short*)(smem + ASZ);

    const int K = BK * KOUT;
    const int mb = blockIdx.x;
    const int nb = blockIdx.y;
    const int dir = nb >> 2, ncol0 = (nb & 3) * 128;
    const int row0 = mb * 128;
    const unsigned short* Asrc = A + (size_t)row0 * lda;
    const unsigned short* Bsrc = W + (size_t)dir * 512 * K + (size_t)ncol0 * K;
    unsigned short* out = gx + (size_t)dir * Mn * G4;

    const int tid = threadIdx.x;
    const int w = tid >> 6, l = tid & 63;
    const int q = l >> 4, i = l & 15;
    const int wm = w >> 1, wn = w & 1;

    f32x4 acc[4][4];
#pragma unroll
    for (int a = 0; a < 4; ++a)
#pragma unroll
        for (int b = 0; b < 4; ++b) acc[a][b] = f32x4{0.f, 0.f, 0.f, 0.f};

    for (int ko = 0; ko < KOUT; ++ko) {
#pragma unroll
        for (int it = 0; it < (128 * GR) / 256; ++it) {
            int g = it * 256 + tid;
            int row = g / GR, p = g % GR;
            int gi = p ^ (row & SWM);
            gload16(Asrc + (size_t)row * lda + ko * BK + gi * 8,
                    (char*)Atile + g * 16);
        }
#pragma unroll
        for (int it = 0; it < (128 * GR) / 256; ++it) {
            int g = it * 256 + tid;
            int row = g / GR, p = g % GR;
            int gi = p ^ (row & SWM);
            gload16(Bsrc + (size_t)row * K + ko * BK + gi * 8,
                    (char*)Btile + g * 16);
        }
        __syncthreads();
#pragma unroll
        for (int kf = 0; kf < BK / 32; ++kf) {
            s16x8 af[4], bf[4];
#pragma unroll
            for (int mt = 0; mt < 4; ++mt) {
                int ar = wm * 64 + mt * 16 + i;
                int p = (kf * 4 + q) ^ (ar & SWM);
                af[mt] = *(const s16x8*)((char*)Atile + (ar * GR + p) * 16);
            }
#pragma unroll
            for (int nt = 0; nt < 4; ++nt) {
                int br = wn * 64 + nt * 16 + i;
                int p = (kf * 4 + q) ^ (br & SWM);
                bf[nt] = *(const s16x8*)((char*)Btile + (br * GR + p) * 16);
            }
#pragma unroll
            for (int mt = 0; mt < 4; ++mt)
#pragma unroll
                for (int nt = 0; nt < 4; ++nt)
                    acc[mt][nt] = __builtin_amdgcn_mfma_f32_16x16x32_bf16(
                        af[mt], bf[nt], acc[mt][nt], 0, 0, 0);
        }
        __syncthreads();
    }

    float* gbufw = (float*)(smem + GOFF) + w * (16 * 68);
#pragma unroll
    for (int mt = 0; mt < 4; ++mt) {
#pragma unroll
        for (int nt = 0; nt < 4; ++nt)
#pragma unroll
            for (int r = 0; r < 4; ++r)
                gbufw[(q * 4 + r) * 68 + nt * 16 + i] = acc[mt][nt][r];
        __syncthreads();
#pragma unroll
        for (int it2 = 0; it2 < 2; ++it2) {
            int rr = (l >> 3) + it2 * 8;
            int cc = (l & 7) * 8;
            const float* gsrc = gbufw + rr * 68 + cc;
            uint4 pv;
            pv.x = pk2(gsrc[0], gsrc[1]);
            pv.y = pk2(gsrc[2], gsrc[3]);
            pv.z = pk2(gsrc[4], gsrc[5]);
            pv.w = pk2(gsrc[6], gsrc[7]);
            *(uint4*)(out + (size_t)(row0 + wm * 64 + mt * 16 + rr) * G4
                          + ncol0 + wn * 64 + cc) = pv;
        }
        __syncthreads();
    }
}

// ---------------------------------------------------------------------------
// Recurrent sweep v3: all-gates-per-wave j-window partition.
// Wave jw owns cols {g*128 + jw*32 + jh*16 + i} (8 tiles: tt = g*2+jh).
// All 4 gates of cell (m, j) land in lane i (q==0), reg m -> intra-wave act,
// no Gs LDS, ONE barrier/step. hbuf double-buffered (phase = s&1).
// ---------------------------------------------------------------------------
__global__ __launch_bounds__(256, 1)
void lstm_rec(const unsigned short* __restrict__ gx,
              const float* __restrict__ Whf,
              const float* __restrict__ Whb,
              const float* __restrict__ biasf,
              const float* __restrict__ biasb,
              float* __restrict__ y,
              unsigned short* __restrict__ y0b,
              float* __restrict__ hn,
              float* __restrict__ cn,
              int layer)
{
    const int b0  = blockIdx.x * 2;
    const int dir = blockIdx.y;
    const float* Wh   = dir ? Whb : Whf;
    const float* bias = dir ? biasb : biasf;
    const unsigned short* gxd = gx + (size_t)dir * Mn * G4;

    const int tid = threadIdx.x;
    const int jw = tid >> 6;           // wave -> j-window
    const int l  = tid & 63;
    const int q  = l >> 4, i = l & 15;

    __shared__ unsigned short hbuf[2][16][136];   // [phase][row][j], rows>=2 stay 0

    for (int idx = tid; idx < 2 * 16 * 136; idx += 256)
        ((unsigned short*)hbuf)[idx] = 0;

    // W_hh B-frags: tile tt = g*2+jh -> col n = g*128 + jw*32 + jh*16 + i
    s16x8 wh[8][4];
#pragma unroll
    for (int tt = 0; tt < 8; ++tt) {
        int n = (tt >> 1) * 128 + jw * 32 + (tt & 1) * 16 + i;
#pragma unroll
        for (int kf = 0; kf < 4; ++kf)
            wh[tt][kf] = cvt8v(Wh + (size_t)n * Hn + kf * 32 + q * 8);
    }
    // bias per tile (valid for act lanes l<16; dup elsewhere harmless)
    float bs[8];
#pragma unroll
    for (int tt = 0; tt < 8; ++tt)
        bs[tt] = bias[(tt >> 1) * 128 + jw * 32 + (tt & 1) * 16 + i];

    float cst[2][2] = {{0.f, 0.f}, {0.f, 0.f}};   // c[m][jh]
    float hfin[2][2] = {{0.f, 0.f}, {0.f, 0.f}};

    // 2-deep gx prefetch ping-pong (raw bf16 bits; all lanes load dup of i<16)
    unsigned short gpre[2][2][8];                 // [buf][m][tt]
#pragma unroll
    for (int pb = 0; pb < 2; ++pb) {
        int s0 = pb;
        int t0 = dir ? (Tn - 1 - s0) : s0;
#pragma unroll
        for (int m = 0; m < 2; ++m) {
            const unsigned short* gb = gxd + ((size_t)(b0 + m) * Tn + t0) * G4
                                           + jw * 32 + i;
#pragma unroll
            for (int tt = 0; tt < 8; ++tt)
                gpre[pb][m][tt] = gb[(tt >> 1) * 128 + (tt & 1) * 16];
        }
    }

    const f32x4 zf = f32x4{0.f, 0.f, 0.f, 0.f};

    __syncthreads();   // covers hbuf zero-init

    auto step = [&](int s, int pb) {
        const int t = dir ? (Tn - 1 - s) : s;
        const int p = s & 1;

        // unpack this step's gx (loaded 2 steps ago), then refill buffer
        float gxv[2][8];
#pragma unroll
        for (int m = 0; m < 2; ++m)
#pragma unroll
            for (int tt = 0; tt < 8; ++tt)
                gxv[m][tt] = b2f(gpre[pb][m][tt]);
        {
            int s2 = (s + 2 < Tn) ? (s + 2) : s;
            int t2 = dir ? (Tn - 1 - s2) : s2;
#pragma unroll
            for (int m = 0; m < 2; ++m) {
                const unsigned short* gb = gxd + ((size_t)(b0 + m) * Tn + t2) * G4
                                               + jw * 32 + i;
#pragma unroll
                for (int tt = 0; tt < 8; ++tt)
                    gpre[pb][m][tt] = gb[(tt >> 1) * 128 + (tt & 1) * 16];
            }
        }

        // MFMA: read h (phase p), tile-major so early tiles' act can co-issue
        s16x8 ah[4];
#pragma unroll
        for (int kf = 0; kf < 4; ++kf)
            ah[kf] = *(const s16x8*)(&hbuf[p][i][kf * 32 + q * 8]);
        f32x4 acc[8];
#pragma unroll
        for (int tt = 0; tt < 8; ++tt) {
            acc[tt] = __builtin_amdgcn_mfma_f32_16x16x32_bf16(ah[0], wh[tt][0], zf, 0, 0, 0);
#pragma unroll
            for (int kf = 1; kf < 4; ++kf)
                acc[tt] = __builtin_amdgcn_mfma_f32_16x16x32_bf16(ah[kf], wh[tt][kf], acc[tt], 0, 0, 0);
        }

        // act: lanes 0-15 hold rows 0,1 (reg m) for all 4 gates of 4 cells
        if (l < 16) {
#pragma unroll
            for (int m = 0; m < 2; ++m) {
#pragma unroll
                for (int jh = 0; jh < 2; ++jh) {
                    float gi = acc[0 + jh][m] + gxv[m][0 + jh] + bs[0 + jh];
                    float gf = acc[2 + jh][m] + gxv[m][2 + jh] + bs[2 + jh];
                    float gg = acc[4 + jh][m] + gxv[m][4 + jh] + bs[4 + jh];
                    float go = acc[6 + jh][m] + gxv[m][6 + jh] + bs[6 + jh];
                    float iv = sigm(gi), fv = sigm(gf), ov = sigm(go);
                    float gv = tanh_f(gg);
                    float c = fv * cst[m][jh] + iv * gv;
                    cst[m][jh] = c;
                    float h = ov * tanh_f(c);
                    hfin[m][jh] = h;
                    int j = jw * 32 + jh * 16 + i;
                    hbuf[p ^ 1][m][j] = f2b(h);
                    if (layer == 0)
                        y0b[((size_t)(b0 + m) * Tn + t) * 256 + dir * 128 + j] = f2b(h);
                    else
                        y[((size_t)(b0 + m) * Tn + t) * 256 + dir * 128 + j] = h;
                }
            }
        }
        ldsbar();   // ONE barrier: h(phase p^1) writes -> next step's reads
    };

    for (int s = 0; s < Tn; s += 2) {
        step(s, 0);
        step(s + 1, 1);
    }

    const int slot = layer * 2 + dir;
    if (l < 16) {
#pragma unroll
        for (int m = 0; m < 2; ++m)
#pragma unroll
            for (int jh = 0; jh < 2; ++jh) {
                int j = jw * 32 + jh * 16 + i;
                hn[((size_t)slot * Bn + b0 + m) * Hn + j] = hfin[m][jh];
                cn[((size_t)slot * Bn + b0 + m) * Hn + j] = cst[m][jh];
            }
    }
}

// ---------------------------------------------------------------------------
extern "C" void kernel_launch(void* const* d_in, const int* in_sizes, int n_in,
                              void* d_out, int out_size, void* d_ws, size_t ws_size,
                              hipStream_t stream)
{
    const float* x     = (const float*)d_in[0];
    const float* wih0f = (const float*)d_in[1];
    const float* whh0f = (const float*)d_in[2];
    const float* b0f   = (const float*)d_in[3];
    const float* wih0b = (const float*)d_in[4];
    const float* whh0b = (const float*)d_in[5];
    const float* b0b   = (const float*)d_in[6];
    const float* wih1f = (const float*)d_in[7];
    const float* whh1f = (const float*)d_in[8];
    const float* b1f   = (const float*)d_in[9];
    const float* wih1b = (const float*)d_in[10];
    const float* whh1b = (const float*)d_in[11];
    const float* b1b   = (const float*)d_in[12];

    float* y  = (float*)d_out;                       // [B][T][256] fp32 (final)
    float* hn = y + (size_t)Mn * 256;                // [4][B][128]
    float* cn = hn + (size_t)4 * Bn * Hn;            // [4][B][128]
    unsigned short* gx = (unsigned short*)d_ws;      // [2][M][512] bf16 = 256 MiB

    unsigned short* scr  = (unsigned short*)d_out;
    unsigned short* y0b  = scr;                              // [M][256] bf16
    unsigned short* xb   = scr + (size_t)Mn * 256;           // [M][32]
    unsigned short* w0bf = xb  + (size_t)Mn * 32;            // [2][512][32]
    unsigned short* w1bf = w0bf + 2 * 512 * 32;              // [2][512][256]

    prep<<<2048, 256, 0, stream>>>(x, wih0f, wih0b, wih1f, wih1b, xb, w0bf, w1bf);

    dim3 gg(1024, 8), gb(256);
    dim3 rg(128, 2), rb(256);

    gemm_tile<32, 1><<<gg, gb, 0, stream>>>(xb, 32, w0bf, gx);
    lstm_rec<<<rg, rb, 0, stream>>>(gx, whh0f, whh0b, b0f, b0b, y, y0b, hn, cn, 0);
    gemm_tile<128, 2><<<gg, gb, 0, stream>>>(y0b, 256, w1bf, gx);
    lstm_rec<<<rg, rb, 0, stream>>>(gx, whh1f, whh1b, b1f, b1b, y, y0b, hn, cn, 1);
}

// Round 7
// 1033.766 us; speedup vs baseline: 1.3954x; 1.3954x over previous
//
#include <hip/hip_runtime.h>
#include <hip/hip_bf16.h>
#include <stdint.h>

#define Bn 256
#define Tn 512
#define Hn 128
#define G4 512   // 4*H
#define Mn (Bn*Tn)

typedef __attribute__((ext_vector_type(8))) short s16x8;
typedef __attribute__((ext_vector_type(4))) float f32x4;

__device__ __forceinline__ float b2f(unsigned short u) {
    union { unsigned int i; float f; } v; v.i = ((unsigned int)u) << 16; return v.f;
}
__device__ __forceinline__ unsigned short f2b(float f) {
    union { float f; unsigned int i; } v; v.f = f;
    unsigned int x = v.i;
    unsigned int r = (x + 0x7FFFu + ((x >> 16) & 1u)) >> 16;
    return (unsigned short)r;
}
__device__ __forceinline__ unsigned int pk2(float a, float b) {
    __hip_bfloat162 t = __float22bfloat162_rn(make_float2(a, b));
    union { __hip_bfloat162 v; unsigned int u; } c; c.v = t; return c.u;
}
__device__ __forceinline__ s16x8 cvt8v(const float* p) {
    f32x4 a = *(const f32x4*)p;
    f32x4 b = *(const f32x4*)(p + 4);
    s16x8 r;
    r[0] = (short)f2b(a[0]); r[1] = (short)f2b(a[1]);
    r[2] = (short)f2b(a[2]); r[3] = (short)f2b(a[3]);
    r[4] = (short)f2b(b[0]); r[5] = (short)f2b(b[1]);
    r[6] = (short)f2b(b[2]); r[7] = (short)f2b(b[3]);
    return r;
}
__device__ __forceinline__ float sigm(float x) {
    return __builtin_amdgcn_rcpf(1.f + __expf(-x));
}
__device__ __forceinline__ float tanh_f(float x) {
    return 1.f - 2.f * __builtin_amdgcn_rcpf(1.f + __expf(2.f * x));
}
__device__ __forceinline__ void gload16(const void* gsrc, void* lds) {
    __builtin_amdgcn_global_load_lds(
        (const __attribute__((address_space(1))) unsigned int*)gsrc,
        (__attribute__((address_space(3))) unsigned int*)lds, 16, 0, 0);
}
// LDS-only barrier: waits DS ops but NOT outstanding global loads/stores.
__device__ __forceinline__ void ldsbar() {
    asm volatile("s_waitcnt lgkmcnt(0)\n\ts_barrier" ::: "memory");
}

// ---------------------------------------------------------------------------
// prep (unchanged, passing)
// ---------------------------------------------------------------------------
__global__ __launch_bounds__(256)
void prep(const float* __restrict__ x,
          const float* __restrict__ w0f, const float* __restrict__ w0b,
          const float* __restrict__ w1f, const float* __restrict__ w1b,
          unsigned short* __restrict__ xb,
          unsigned short* __restrict__ w0bf,
          unsigned short* __restrict__ w1bf)
{
    int tid = blockIdx.x * 256 + threadIdx.x;
    int nthr = gridDim.x * 256;
    for (int idx = tid; idx < Mn * 32; idx += nthr) {
        int row = idx >> 5, col = idx & 31;
        xb[idx] = f2b(col < 24 ? x[row * 24 + col] : 0.f);
    }
    for (int idx = tid; idx < 2 * 512 * 32; idx += nthr) {
        int d = idx >> 14, rem = idx & 16383;
        int n = rem >> 5, col = rem & 31;
        const float* w = d ? w0b : w0f;
        w0bf[idx] = f2b(col < 24 ? w[n * 24 + col] : 0.f);
    }
    for (int idx = tid; idx < 2 * 512 * 256; idx += nthr) {
        int d = idx >> 17, rem = idx & 131071;
        const float* w = d ? w1b : w1f;
        w1bf[idx] = f2b(w[rem]);
    }
}

// ---------------------------------------------------------------------------
// Tiled GEMM (unchanged, passing)
// ---------------------------------------------------------------------------
template<int BK, int KOUT>
__global__ __launch_bounds__(256, 2)
void gemm_tile(const unsigned short* __restrict__ A, int lda,
               const unsigned short* __restrict__ W,
               unsigned short* __restrict__ gx)
{
    constexpr int GR = BK / 8;
    constexpr int SWM = (GR >= 8) ? 7 : (GR - 1);
    constexpr int ASZ = 128 * BK * 2;
    constexpr int GOFF = (BK == 128) ? 0 : 2 * ASZ;
    constexpr int SMEM = 2 * ASZ + ((BK == 128) ? 0 : 4 * 16 * 68 * 4);
    __shared__ char smem[SMEM];
    unsigned short* Atile = (unsigned short*)smem;
    unsigned short* Btile = (unsigned short*)(smem + ASZ);

    const int K = BK * KOUT;
    const int mb = blockIdx.x;
    const int nb = blockIdx.y;
    const int dir = nb >> 2, ncol0 = (nb & 3) * 128;
    const int row0 = mb * 128;
    const unsigned short* Asrc = A + (size_t)row0 * lda;
    const unsigned short* Bsrc = W + (size_t)dir * 512 * K + (size_t)ncol0 * K;
    unsigned short* out = gx + (size_t)dir * Mn * G4;

    const int tid = threadIdx.x;
    const int w = tid >> 6, l = tid & 63;
    const int q = l >> 4, i = l & 15;
    const int wm = w >> 1, wn = w & 1;

    f32x4 acc[4][4];
#pragma unroll
    for (int a = 0; a < 4; ++a)
#pragma unroll
        for (int b = 0; b < 4; ++b) acc[a][b] = f32x4{0.f, 0.f, 0.f, 0.f};

    for (int ko = 0; ko < KOUT; ++ko) {
#pragma unroll
        for (int it = 0; it < (128 * GR) / 256; ++it) {
            int g = it * 256 + tid;
            int row = g / GR, p = g % GR;
            int gi = p ^ (row & SWM);
            gload16(Asrc + (size_t)row * lda + ko * BK + gi * 8,
                    (char*)Atile + g * 16);
        }
#pragma unroll
        for (int it = 0; it < (128 * GR) / 256; ++it) {
            int g = it * 256 + tid;
            int row = g / GR, p = g % GR;
            int gi = p ^ (row & SWM);
            gload16(Bsrc + (size_t)row * K + ko * BK + gi * 8,
                    (char*)Btile + g * 16);
        }
        __syncthreads();
#pragma unroll
        for (int kf = 0; kf < BK / 32; ++kf) {
            s16x8 af[4], bf[4];
#pragma unroll
            for (int mt = 0; mt < 4; ++mt) {
                int ar = wm * 64 + mt * 16 + i;
                int p = (kf * 4 + q) ^ (ar & SWM);
                af[mt] = *(const s16x8*)((char*)Atile + (ar * GR + p) * 16);
            }
#pragma unroll
            for (int nt = 0; nt < 4; ++nt) {
                int br = wn * 64 + nt * 16 + i;
                int p = (kf * 4 + q) ^ (br & SWM);
                bf[nt] = *(const s16x8*)((char*)Btile + (br * GR + p) * 16);
            }
#pragma unroll
            for (int mt = 0; mt < 4; ++mt)
#pragma unroll
                for (int nt = 0; nt < 4; ++nt)
                    acc[mt][nt] = __builtin_amdgcn_mfma_f32_16x16x32_bf16(
                        af[mt], bf[nt], acc[mt][nt], 0, 0, 0);
        }
        __syncthreads();
    }

    float* gbufw = (float*)(smem + GOFF) + w * (16 * 68);
#pragma unroll
    for (int mt = 0; mt < 4; ++mt) {
#pragma unroll
        for (int nt = 0; nt < 4; ++nt)
#pragma unroll
            for (int r = 0; r < 4; ++r)
                gbufw[(q * 4 + r) * 68 + nt * 16 + i] = acc[mt][nt][r];
        __syncthreads();
#pragma unroll
        for (int it2 = 0; it2 < 2; ++it2) {
            int rr = (l >> 3) + it2 * 8;
            int cc = (l & 7) * 8;
            const float* gsrc = gbufw + rr * 68 + cc;
            uint4 pv;
            pv.x = pk2(gsrc[0], gsrc[1]);
            pv.y = pk2(gsrc[2], gsrc[3]);
            pv.z = pk2(gsrc[4], gsrc[5]);
            pv.w = pk2(gsrc[6], gsrc[7]);
            *(uint4*)(out + (size_t)(row0 + wm * 64 + mt * 16 + rr) * G4
                          + ncol0 + wn * 64 + cc) = pv;
        }
        __syncthreads();
    }
}

// ---------------------------------------------------------------------------
// Recurrent sweep v4: v2 structure, but 512-thread blocks (8 waves, 2/SIMD)
// handling 4 sequences each -> MFMA/act/LDS from different waves overlap.
// Wave w owns 64 gate-cols (4 tiles x 4 kf = 16 MFMAs); rows 0-3 = 4 seqs.
// Gs padded [512][5] (stride 5 -> conflict-free act reads, gcd(5,32)=1).
// ---------------------------------------------------------------------------
__global__ __launch_bounds__(512, 1)
void lstm_rec(const unsigned short* __restrict__ gx,
              const float* __restrict__ Whf,
              const float* __restrict__ Whb,
              const float* __restrict__ biasf,
              const float* __restrict__ biasb,
              float* __restrict__ y,
              unsigned short* __restrict__ y0b,
              float* __restrict__ hn,
              float* __restrict__ cn,
              int layer)
{
    const int b0  = blockIdx.x * 4;
    const int dir = blockIdx.y;
    const float* Wh   = dir ? Whb : Whf;
    const float* bias = dir ? biasb : biasf;
    const unsigned short* gxd = gx + (size_t)dir * Mn * G4;

    const int tid = threadIdx.x;
    const int w = tid >> 6, l = tid & 63;
    const int q = l >> 4, i = l & 15;

    __shared__ unsigned short hbuf[16][136];   // rows 0-3 live, 4-15 stay 0
    __shared__ float Gs[512 * 5];              // [n][m], stride 5 (pad)

    for (int idx = tid; idx < 16 * 136; idx += 512)
        ((unsigned short*)hbuf)[idx] = 0;

    // W_hh B-frags: wave w owns tiles tt=0..3 -> col n = w*64 + tt*16 + i
    s16x8 wh[4][4];
#pragma unroll
    for (int tt = 0; tt < 4; ++tt) {
        int n = w * 64 + tt * 16 + i;
#pragma unroll
        for (int kf = 0; kf < 4; ++kf)
            wh[tt][kf] = cvt8v(Wh + (size_t)n * Hn + kf * 32 + q * 8);
    }

    // per-thread cell: m in {0..3}, hidden index j
    const int m = tid >> 7;
    const int j = tid & 127;
    const int b = b0 + m;
    const float bi = bias[j],       bf = bias[128 + j];
    const float bg = bias[256 + j], bo = bias[384 + j];
    float c = 0.f, hlast = 0.f;

    // 8-deep gx register prefetch ping-pong (raw bf16 bits)
    unsigned short bufA[4][8], bufB[4][8];
#pragma unroll
    for (int f = 0; f < 8; ++f) {
        int t = dir ? (Tn - 1 - f) : f;
        const unsigned short* gp = gxd + ((size_t)b * Tn + t) * G4;
        bufA[0][f] = gp[j];
        bufA[1][f] = gp[128 + j];
        bufA[2][f] = gp[256 + j];
        bufA[3][f] = gp[384 + j];
    }

    __syncthreads();   // covers hbuf zero-init

    const f32x4 zf = f32x4{0.f, 0.f, 0.f, 0.f};

    auto do8 = [&](unsigned short (&useB)[4][8], unsigned short (&ldB)[4][8],
                   int sb) {
#pragma unroll
        for (int f = 0; f < 8; ++f) {
            const int s = sb + f;
            const int t = dir ? (Tn - 1 - s) : s;

            // MFMA: gates[n] = h @ W_hh^T (rows 0-3 used)
            s16x8 ah[4];
#pragma unroll
            for (int kf = 0; kf < 4; ++kf)
                ah[kf] = *(const s16x8*)(&hbuf[i][kf * 32 + q * 8]);
            f32x4 acc[4];
#pragma unroll
            for (int tt = 0; tt < 4; ++tt) {
                acc[tt] = __builtin_amdgcn_mfma_f32_16x16x32_bf16(ah[0], wh[tt][0], zf, 0, 0, 0);
#pragma unroll
                for (int kf = 1; kf < 4; ++kf)
                    acc[tt] = __builtin_amdgcn_mfma_f32_16x16x32_bf16(ah[kf], wh[tt][kf], acc[tt], 0, 0, 0);
            }
            // rows 0-3 live in q==0 lanes' regs 0-3
            if (q == 0) {
#pragma unroll
                for (int tt = 0; tt < 4; ++tt) {
                    int n = w * 64 + tt * 16 + i;
#pragma unroll
                    for (int r = 0; r < 4; ++r)
                        Gs[n * 5 + r] = acc[tt][r];
                }
            }
            // issue gx prefetch for step s+8
            {
                int sl = (s + 8 < Tn) ? (s + 8) : s;
                int tl = dir ? (Tn - 1 - sl) : sl;
                const unsigned short* gp = gxd + ((size_t)b * Tn + tl) * G4;
                ldB[0][f] = gp[j];
                ldB[1][f] = gp[128 + j];
                ldB[2][f] = gp[256 + j];
                ldB[3][f] = gp[384 + j];
            }
            ldsbar();   // barrier 1: Gs write -> Gs read

            float gi = Gs[j * 5 + m]         + b2f(useB[0][f]) + bi;
            float gf = Gs[(128 + j) * 5 + m] + b2f(useB[1][f]) + bf;
            float gg = Gs[(256 + j) * 5 + m] + b2f(useB[2][f]) + bg;
            float go = Gs[(384 + j) * 5 + m] + b2f(useB[3][f]) + bo;
            float iv = sigm(gi), fv = sigm(gf), ov = sigm(go);
            float gv = tanh_f(gg);
            c = fv * c + iv * gv;
            float h = ov * tanh_f(c);
            hlast = h;
            unsigned short hb = f2b(h);
            hbuf[m][j] = hb;
            if (layer == 0)
                y0b[((size_t)b * Tn + t) * 256 + dir * 128 + j] = hb;
            else
                y[((size_t)b * Tn + t) * 256 + dir * 128 + j] = h;

            ldsbar();   // barrier 2: hbuf write -> next step's A-frag read
        }
    };

    for (int sb = 0; sb < Tn; sb += 16) {
        do8(bufA, bufB, sb);
        do8(bufB, bufA, sb + 8);
    }

    const int slot = layer * 2 + dir;
    hn[((size_t)slot * Bn + b) * Hn + j] = hlast;
    cn[((size_t)slot * Bn + b) * Hn + j] = c;
}

// ---------------------------------------------------------------------------
extern "C" void kernel_launch(void* const* d_in, const int* in_sizes, int n_in,
                              void* d_out, int out_size, void* d_ws, size_t ws_size,
                              hipStream_t stream)
{
    const float* x     = (const float*)d_in[0];
    const float* wih0f = (const float*)d_in[1];
    const float* whh0f = (const float*)d_in[2];
    const float* b0f   = (const float*)d_in[3];
    const float* wih0b = (const float*)d_in[4];
    const float* whh0b = (const float*)d_in[5];
    const float* b0b   = (const float*)d_in[6];
    const float* wih1f = (const float*)d_in[7];
    const float* whh1f = (const float*)d_in[8];
    const float* b1f   = (const float*)d_in[9];
    const float* wih1b = (const float*)d_in[10];
    const float* whh1b = (const float*)d_in[11];
    const float* b1b   = (const float*)d_in[12];

    float* y  = (float*)d_out;                       // [B][T][256] fp32 (final)
    float* hn = y + (size_t)Mn * 256;                // [4][B][128]
    float* cn = hn + (size_t)4 * Bn * Hn;            // [4][B][128]
    unsigned short* gx = (unsigned short*)d_ws;      // [2][M][512] bf16 = 256 MiB

    unsigned short* scr  = (unsigned short*)d_out;
    unsigned short* y0b  = scr;                              // [M][256] bf16
    unsigned short* xb   = scr + (size_t)Mn * 256;           // [M][32]
    unsigned short* w0bf = xb  + (size_t)Mn * 32;            // [2][512][32]
    unsigned short* w1bf = w0bf + 2 * 512 * 32;              // [2][512][256]

    prep<<<2048, 256, 0, stream>>>(x, wih0f, wih0b, wih1f, wih1b, xb, w0bf, w1bf);

    dim3 gg(1024, 8), gb(256);
    dim3 rg(64, 2), rb(512);

    gemm_tile<32, 1><<<gg, gb, 0, stream>>>(xb, 32, w0bf, gx);
    lstm_rec<<<rg, rb, 0, stream>>>(gx, whh0f, whh0b, b0f, b0b, y, y0b, hn, cn, 0);
    gemm_tile<128, 2><<<gg, gb, 0, stream>>>(y0b, 256, w1bf, gx);
    lstm_rec<<<rg, rb, 0, stream>>>(gx, whh1f, whh1b, b1f, b1b, y, y0b, hn, cn, 1);
}